// Round 7
// baseline (381.311 us; speedup 1.0000x reference)
//
#include <hip/hip_runtime.h>

// Problem constants (from reference):
//   B=8, S=4, L=512, H=768  -> hidden (8, 2048, 768) fp32 (50 MB)
//   N_SPANS=4096, T_MAX=16, N_PAIRS=16384
//   out[p] = [repr(pair_i[p]) | repr(pair_j[p])], repr = [first|mean|last] (9 KB)
//
// R7 structure: R6's barrier-free scalar scatter, with the 4-kernel index
// chain (zero/count/scan/fill, ~20-25 us of serial launches) collapsed into
// ONE single-block kernel: counts/cursor in LDS (16 KB), pairs read twice
// (512 KB through one CU), targets written once. Dispatches: 5 -> 2.
//   Main kernel (unchanged, tied-best at 363.9):
//   - block s computes [first|mean|last] in registers (clamped 16-load gather)
//   - scalarized metadata (readfirstlane -> SALU/s_load)
//   - barrier-free scatter to all (pair,side) targets, nt stores (302 MB
//     stream, never re-read).

#define SPAN_HF4  192          // H / 4 float4s
#define SPAN_TMAX 16
#define SPAN_SL   2048         // S * L
#define REPR_F4   576          // 3 * 192 float4 per span
#define OUT_F4    1152         // 2 * 576 float4 per pair
#define MAX_SPANS 4096         // LDS counts capacity (16 KB)

// Native clang vector: __builtin_nontemporal_store rejects HIP_vector_type.
typedef float f4nt __attribute__((ext_vector_type(4)));

__device__ __forceinline__ void nt_store_f4(const float4 v, float4* p) {
    f4nt t;
    t.x = v.x; t.y = v.y; t.z = v.z; t.w = v.w;
    __builtin_nontemporal_store(t, reinterpret_cast<f4nt*>(p));
}

__device__ __forceinline__ void store_repr(float4* o, int c,
                                           const float4 a0, const float4 a1,
                                           const float4 a2) {
    nt_store_f4(a0, &o[c]);
    nt_store_f4(a1, &o[SPAN_HF4 + c]);
    nt_store_f4(a2, &o[2 * SPAN_HF4 + c]);
}

// ------------------------------------- index pass: ONE single-block kernel

__global__ __launch_bounds__(1024)
void build_index_kernel(const int* __restrict__ pair_i,
                        const int* __restrict__ pair_j, int n_pairs,
                        int* __restrict__ offsets,   // n_spans+1 (global)
                        int* __restrict__ targets,   // 2*n_pairs (global)
                        int n_spans)
{
    __shared__ int cnt[MAX_SPANS];   // counts, then cursor
    __shared__ int sums[1024];
    const int t = threadIdx.x;

    // zero
    for (int i = t; i < n_spans; i += 1024) cnt[i] = 0;
    __syncthreads();

    // count (LDS atomics)
    for (int p = t; p < n_pairs; p += 1024) {
        atomicAdd(&cnt[pair_i[p]], 1);
        atomicAdd(&cnt[pair_j[p]], 1);
    }
    __syncthreads();

    // exclusive scan over <=4096 counts: 4 per thread + Hillis-Steele.
    const int base = t * 4;
    int c0 = 0, c1 = 0, c2 = 0, c3 = 0;
    if (base     < n_spans) c0 = cnt[base];
    if (base + 1 < n_spans) c1 = cnt[base + 1];
    if (base + 2 < n_spans) c2 = cnt[base + 2];
    if (base + 3 < n_spans) c3 = cnt[base + 3];
    sums[t] = c0 + c1 + c2 + c3;
    __syncthreads();
    for (int off = 1; off < 1024; off <<= 1) {
        const int v = (t >= off) ? sums[t - off] : 0;
        __syncthreads();
        sums[t] += v;
        __syncthreads();
    }
    const int excl = (t == 0) ? 0 : sums[t - 1];
    const int o0 = excl, o1 = o0 + c0, o2 = o1 + c1, o3 = o2 + c2;
    __syncthreads();   // all reads of cnt done before overwrite as cursor
    if (base     < n_spans) { offsets[base]     = o0; cnt[base]     = o0; }
    if (base + 1 < n_spans) { offsets[base + 1] = o1; cnt[base + 1] = o1; }
    if (base + 2 < n_spans) { offsets[base + 2] = o2; cnt[base + 2] = o2; }
    if (base + 3 < n_spans) { offsets[base + 3] = o3; cnt[base + 3] = o3; }
    if (t == 1023) offsets[n_spans] = sums[1023];   // total = 2*n_pairs
    __syncthreads();

    // fill (LDS cursor atomics)
    for (int p = t; p < n_pairs; p += 1024) {
        const int a = atomicAdd(&cnt[pair_i[p]], 1);
        targets[a] = p * 2;          // side 0 (i-half)
        const int b = atomicAdd(&cnt[pair_j[p]], 1);
        targets[b] = p * 2 + 1;      // side 1 (j-half)
    }
}

// ------------------------------------------------------------------ main pass

__global__ __launch_bounds__(192)
void span_scatter_kernel(
    const float4* __restrict__ hidden,    // (B, SL, HF4)
    const int*    __restrict__ span_doc,
    const int*    __restrict__ span_tok,  // (N_SPANS, TMAX)
    const int*    __restrict__ span_len,
    const int*    __restrict__ offsets,   // (n_spans+1)
    const int*    __restrict__ targets,   // (2*n_pairs): p*2+side
    float4*       __restrict__ out,       // (N_PAIRS, 1152)
    int n_spans)
{
    const int c = threadIdx.x;            // 0..191
    const int s = blockIdx.x;
    if (s >= n_spans) return;

    // Block-uniform metadata -> SGPRs (compiler can't prove uniformity).
    const int doc   = __builtin_amdgcn_readfirstlane(span_doc[s]);
    const int len   = __builtin_amdgcn_readfirstlane(span_len[s]);
    const int start = __builtin_amdgcn_readfirstlane(offsets[s]);
    const int end   = __builtin_amdgcn_readfirstlane(offsets[s + 1]);
    const int* toks = span_tok + s * SPAN_TMAX;
    const float4* base = hidden + (size_t)doc * (SPAN_SL * SPAN_HF4);

    // Gather: t = 0 peeled (len >= 1 always); remaining 15 loads clamped to
    // len-1 (valid addr, cache-hit) => 16 unconditional independent loads.
    float4 first, last;
    float sx, sy, sz, sw;
    {
        const float4 v = base[(size_t)toks[0] * SPAN_HF4 + c];
        first = v; last = v;
        sx = v.x; sy = v.y; sz = v.z; sw = v.w;
    }
    #pragma unroll
    for (int t = 1; t < SPAN_TMAX; ++t) {
        const int tc = (t < len) ? t : (len - 1);
        const float4 v = base[(size_t)toks[tc] * SPAN_HF4 + c];
        last = v;
        const float m = (t < len) ? 1.f : 0.f;
        sx += v.x * m; sy += v.y * m; sz += v.z * m; sw += v.w * m;
    }
    const float inv = 1.0f / (float)len;
    const float4 a1 = make_float4(sx * inv, sy * inv, sz * inv, sw * inv);

    // Scatter: uniform (SGPR) target indices, 4-way unrolled; stores are
    // fire-and-forget (no barriers, drain only at kernel end).
    int k = start;
    for (; k + 4 <= end; k += 4) {
        const int t0 = __builtin_amdgcn_readfirstlane(targets[k]);
        const int t1 = __builtin_amdgcn_readfirstlane(targets[k + 1]);
        const int t2 = __builtin_amdgcn_readfirstlane(targets[k + 2]);
        const int t3 = __builtin_amdgcn_readfirstlane(targets[k + 3]);
        store_repr(out + (size_t)(t0 >> 1) * OUT_F4 + (size_t)(t0 & 1) * REPR_F4,
                   c, first, a1, last);
        store_repr(out + (size_t)(t1 >> 1) * OUT_F4 + (size_t)(t1 & 1) * REPR_F4,
                   c, first, a1, last);
        store_repr(out + (size_t)(t2 >> 1) * OUT_F4 + (size_t)(t2 & 1) * REPR_F4,
                   c, first, a1, last);
        store_repr(out + (size_t)(t3 >> 1) * OUT_F4 + (size_t)(t3 & 1) * REPR_F4,
                   c, first, a1, last);
    }
    for (; k < end; ++k) {
        const int tv = __builtin_amdgcn_readfirstlane(targets[k]);
        store_repr(out + (size_t)(tv >> 1) * OUT_F4 + (size_t)(tv & 1) * REPR_F4,
                   c, first, a1, last);
    }
}

// ------------------------------------------- fallback (no workspace needed)

__global__ __launch_bounds__(192)
void span_fused_kernel(
    const float4* __restrict__ hidden,
    const int*    __restrict__ span_doc,
    const int*    __restrict__ span_tok,
    const int*    __restrict__ span_len,
    const int*    __restrict__ pair_i,
    const int*    __restrict__ pair_j,
    float4*       __restrict__ out)
{
    const int p = blockIdx.x;
    const int c = threadIdx.x;
    const int si = pair_i[p];
    const int sj = pair_j[p];
    float4* orow = out + (size_t)p * OUT_F4;

    #pragma unroll
    for (int side = 0; side < 2; ++side) {
        const int s   = side ? sj : si;
        const int doc = span_doc[s];
        const int len = span_len[s];
        const int* toks = span_tok + s * SPAN_TMAX;
        const float4* base = hidden + (size_t)doc * (SPAN_SL * SPAN_HF4);

        float4 first = make_float4(0.f, 0.f, 0.f, 0.f);
        float4 last  = make_float4(0.f, 0.f, 0.f, 0.f);
        float sx = 0.f, sy = 0.f, sz = 0.f, sw = 0.f;
        #pragma unroll
        for (int t = 0; t < SPAN_TMAX; ++t) {
            const int tc = (t < len) ? t : (len - 1);
            const float4 v = base[(size_t)toks[tc] * SPAN_HF4 + c];
            if (t == 0) first = v;
            last = v;
            const float m = (t < len) ? 1.f : 0.f;
            sx += v.x * m; sy += v.y * m; sz += v.z * m; sw += v.w * m;
        }
        const float inv = 1.0f / (float)len;
        float4* o = orow + side * REPR_F4;
        nt_store_f4(first, &o[c]);
        nt_store_f4(make_float4(sx * inv, sy * inv, sz * inv, sw * inv),
                    &o[SPAN_HF4 + c]);
        nt_store_f4(last, &o[2 * SPAN_HF4 + c]);
    }
}

// ----------------------------------------------------------------- launcher

extern "C" void kernel_launch(void* const* d_in, const int* in_sizes, int n_in,
                              void* d_out, int out_size, void* d_ws, size_t ws_size,
                              hipStream_t stream) {
    const float4* hidden  = (const float4*)d_in[0];
    const int* span_doc   = (const int*)d_in[1];
    const int* span_tok   = (const int*)d_in[2];
    const int* span_len   = (const int*)d_in[3];
    const int* pair_i     = (const int*)d_in[4];
    const int* pair_j     = (const int*)d_in[5];
    float4* out           = (float4*)d_out;

    const int n_spans = in_sizes[1];      // 4096
    const int n_pairs = in_sizes[4];      // 16384

    // Workspace layout (16B-aligned sections):
    //   offsets : n_spans+1 ints
    //   targets : 2*n_pairs ints
    auto align16 = [](size_t x) { return (x + 15) & ~(size_t)15; };
    const size_t offsets_b = align16((size_t)(n_spans + 1) * sizeof(int));
    const size_t targets_b = align16((size_t)2 * n_pairs * sizeof(int));
    const size_t need = offsets_b + targets_b;

    if (n_spans <= MAX_SPANS && ws_size >= need) {
        char* ws = (char*)d_ws;
        int* offsets = (int*)(ws);
        int* targets = (int*)(ws + offsets_b);

        build_index_kernel<<<1, 1024, 0, stream>>>(
            pair_i, pair_j, n_pairs, offsets, targets, n_spans);
        span_scatter_kernel<<<n_spans, 192, 0, stream>>>(
            hidden, span_doc, span_tok, span_len, offsets, targets, out, n_spans);
    } else {
        span_fused_kernel<<<n_pairs, 192, 0, stream>>>(
            hidden, span_doc, span_tok, span_len, pair_i, pair_j, out);
    }
}

// Round 8
// 367.662 us; speedup vs baseline: 1.0371x; 1.0371x over previous
//
#include <hip/hip_runtime.h>

// Problem constants (from reference):
//   B=8, S=4, L=512, H=768  -> hidden (8, 2048, 768) fp32 (50 MB)
//   N_SPANS=4096, T_MAX=16, N_PAIRS=16384
//   out[p] = [repr(pair_i[p]) | repr(pair_j[p])], repr = [first|mean|last] (9 KB)
//
// R8 = R6 (best, 363.9) with two write/issue-side changes:
//   1. NORMAL stores instead of nontemporal: the harness fill proves 6.3 TB/s
//      with L2-allocating stores (write-combining -> clean burst eviction);
//      our nt 1 KB chunks scattered at 9 KB granularity bypass that. MALL is
//      memory-side so nt never protected the gather's reads anyway.
//   2. Uniform break at t>=len in the gather (len is SGPR -> s_cbranch, no
//      divergence): halves issued vector loads (avg len 8.5 vs 16) and drops
//      the mask FMAs.
// Index machinery: R6's 4 parallel micro-kernels (R7's single-block fusion
// regressed 17 us -- reverted).

#define SPAN_HF4  192          // H / 4 float4s
#define SPAN_TMAX 16
#define SPAN_SL   2048         // S * L
#define REPR_F4   576          // 3 * 192 float4 per span
#define OUT_F4    1152         // 2 * 576 float4 per pair
#define MAX_SPANS 4096         // scan kernel capacity (1024 thr x 4)

// Native clang vector: __builtin_nontemporal_store rejects HIP_vector_type.
typedef float f4nt __attribute__((ext_vector_type(4)));

__device__ __forceinline__ void nt_store_f4(const float4 v, float4* p) {
    f4nt t;
    t.x = v.x; t.y = v.y; t.z = v.z; t.w = v.w;
    __builtin_nontemporal_store(t, reinterpret_cast<f4nt*>(p));
}

__device__ __forceinline__ void store_repr(float4* o, int c,
                                           const float4 a0, const float4 a1,
                                           const float4 a2) {
    // Normal (L2-allocating) stores: enable write-combining like the fill.
    o[c]                = a0;
    o[SPAN_HF4 + c]     = a1;
    o[2 * SPAN_HF4 + c] = a2;
}

// ---------------------------------------------------------------- inverse map

__global__ void zero_counts_kernel(int* __restrict__ counts, int n) {
    const int i = blockIdx.x * blockDim.x + threadIdx.x;
    if (i < n) counts[i] = 0;
}

__global__ void count_uses_kernel(const int* __restrict__ pair_i,
                                  const int* __restrict__ pair_j,
                                  int* __restrict__ counts, int n_pairs) {
    const int p = blockIdx.x * blockDim.x + threadIdx.x;
    if (p < n_pairs) {
        atomicAdd(&counts[pair_i[p]], 1);
        atomicAdd(&counts[pair_j[p]], 1);
    }
}

// Single-block exclusive scan over <= 4096 counts (1024 threads x 4 elems).
__global__ __launch_bounds__(1024)
void scan_offsets_kernel(const int* __restrict__ counts,
                         int* __restrict__ offsets,   // n_spans+1 entries
                         int* __restrict__ cursor,    // n_spans entries
                         int n_spans) {
    __shared__ int sums[1024];
    const int t = threadIdx.x;
    const int base = t * 4;
    int c0 = 0, c1 = 0, c2 = 0, c3 = 0;
    if (base     < n_spans) c0 = counts[base];
    if (base + 1 < n_spans) c1 = counts[base + 1];
    if (base + 2 < n_spans) c2 = counts[base + 2];
    if (base + 3 < n_spans) c3 = counts[base + 3];
    sums[t] = c0 + c1 + c2 + c3;
    __syncthreads();
    // Hillis-Steele inclusive scan over the 1024 per-thread sums.
    for (int off = 1; off < 1024; off <<= 1) {
        const int v = (t >= off) ? sums[t - off] : 0;
        __syncthreads();
        sums[t] += v;
        __syncthreads();
    }
    const int excl = (t == 0) ? 0 : sums[t - 1];
    const int o0 = excl, o1 = o0 + c0, o2 = o1 + c1, o3 = o2 + c2;
    if (base     < n_spans) { offsets[base]     = o0; cursor[base]     = o0; }
    if (base + 1 < n_spans) { offsets[base + 1] = o1; cursor[base + 1] = o1; }
    if (base + 2 < n_spans) { offsets[base + 2] = o2; cursor[base + 2] = o2; }
    if (base + 3 < n_spans) { offsets[base + 3] = o3; cursor[base + 3] = o3; }
    if (t == 1023) offsets[n_spans] = sums[1023];   // total = 2*n_pairs
}

__global__ void fill_targets_kernel(const int* __restrict__ pair_i,
                                    const int* __restrict__ pair_j,
                                    int* __restrict__ cursor,
                                    int* __restrict__ targets,  // 2*n_pairs
                                    int n_pairs) {
    const int p = blockIdx.x * blockDim.x + threadIdx.x;
    if (p < n_pairs) {
        const int a = atomicAdd(&cursor[pair_i[p]], 1);
        targets[a] = p * 2;          // side 0 (i-half)
        const int b = atomicAdd(&cursor[pair_j[p]], 1);
        targets[b] = p * 2 + 1;      // side 1 (j-half)
    }
}

// ------------------------------------------------------------------ main pass

__global__ __launch_bounds__(192)
void span_scatter_kernel(
    const float4* __restrict__ hidden,    // (B, SL, HF4)
    const int*    __restrict__ span_doc,
    const int*    __restrict__ span_tok,  // (N_SPANS, TMAX)
    const int*    __restrict__ span_len,
    const int*    __restrict__ offsets,   // (n_spans+1)
    const int*    __restrict__ targets,   // (2*n_pairs): p*2+side
    float4*       __restrict__ out,       // (N_PAIRS, 1152)
    int n_spans)
{
    const int c = threadIdx.x;            // 0..191
    const int s = blockIdx.x;
    if (s >= n_spans) return;

    // Block-uniform metadata -> SGPRs (compiler can't prove uniformity).
    const int doc   = __builtin_amdgcn_readfirstlane(span_doc[s]);
    const int len   = __builtin_amdgcn_readfirstlane(span_len[s]);
    const int start = __builtin_amdgcn_readfirstlane(offsets[s]);
    const int end   = __builtin_amdgcn_readfirstlane(offsets[s + 1]);
    const int* toks = span_tok + s * SPAN_TMAX;
    const float4* base = hidden + (size_t)doc * (SPAN_SL * SPAN_HF4);

    // Gather: t = 0 peeled (len >= 1 always); uniform break at t >= len
    // (len is SGPR -> s_cbranch, no divergence). Avg 8.5 loads, no mask FMAs.
    float4 first, last;
    float sx, sy, sz, sw;
    {
        const float4 v = base[(size_t)toks[0] * SPAN_HF4 + c];
        first = v; last = v;
        sx = v.x; sy = v.y; sz = v.z; sw = v.w;
    }
    #pragma unroll
    for (int t = 1; t < SPAN_TMAX; ++t) {
        if (t >= len) break;              // uniform branch
        const float4 v = base[(size_t)toks[t] * SPAN_HF4 + c];
        last = v;
        sx += v.x; sy += v.y; sz += v.z; sw += v.w;
    }
    const float inv = 1.0f / (float)len;
    const float4 a1 = make_float4(sx * inv, sy * inv, sz * inv, sw * inv);

    // Scatter: uniform (SGPR) target indices, 4-way unrolled; stores are
    // fire-and-forget (no barriers, drain only at kernel end).
    int k = start;
    for (; k + 4 <= end; k += 4) {
        const int t0 = __builtin_amdgcn_readfirstlane(targets[k]);
        const int t1 = __builtin_amdgcn_readfirstlane(targets[k + 1]);
        const int t2 = __builtin_amdgcn_readfirstlane(targets[k + 2]);
        const int t3 = __builtin_amdgcn_readfirstlane(targets[k + 3]);
        store_repr(out + (size_t)(t0 >> 1) * OUT_F4 + (size_t)(t0 & 1) * REPR_F4,
                   c, first, a1, last);
        store_repr(out + (size_t)(t1 >> 1) * OUT_F4 + (size_t)(t1 & 1) * REPR_F4,
                   c, first, a1, last);
        store_repr(out + (size_t)(t2 >> 1) * OUT_F4 + (size_t)(t2 & 1) * REPR_F4,
                   c, first, a1, last);
        store_repr(out + (size_t)(t3 >> 1) * OUT_F4 + (size_t)(t3 & 1) * REPR_F4,
                   c, first, a1, last);
    }
    for (; k < end; ++k) {
        const int tv = __builtin_amdgcn_readfirstlane(targets[k]);
        store_repr(out + (size_t)(tv >> 1) * OUT_F4 + (size_t)(tv & 1) * REPR_F4,
                   c, first, a1, last);
    }
}

// ------------------------------------------- fallback (no workspace needed)

__global__ __launch_bounds__(192)
void span_fused_kernel(
    const float4* __restrict__ hidden,
    const int*    __restrict__ span_doc,
    const int*    __restrict__ span_tok,
    const int*    __restrict__ span_len,
    const int*    __restrict__ pair_i,
    const int*    __restrict__ pair_j,
    float4*       __restrict__ out)
{
    const int p = blockIdx.x;
    const int c = threadIdx.x;
    const int si = pair_i[p];
    const int sj = pair_j[p];
    float4* orow = out + (size_t)p * OUT_F4;

    #pragma unroll
    for (int side = 0; side < 2; ++side) {
        const int s   = side ? sj : si;
        const int doc = span_doc[s];
        const int len = span_len[s];
        const int* toks = span_tok + s * SPAN_TMAX;
        const float4* base = hidden + (size_t)doc * (SPAN_SL * SPAN_HF4);

        float4 first = make_float4(0.f, 0.f, 0.f, 0.f);
        float4 last  = make_float4(0.f, 0.f, 0.f, 0.f);
        float sx = 0.f, sy = 0.f, sz = 0.f, sw = 0.f;
        #pragma unroll
        for (int t = 0; t < SPAN_TMAX; ++t) {
            const int tc = (t < len) ? t : (len - 1);
            const float4 v = base[(size_t)toks[tc] * SPAN_HF4 + c];
            if (t == 0) first = v;
            last = v;
            const float m = (t < len) ? 1.f : 0.f;
            sx += v.x * m; sy += v.y * m; sz += v.z * m; sw += v.w * m;
        }
        const float inv = 1.0f / (float)len;
        float4* o = orow + side * REPR_F4;
        nt_store_f4(first, &o[c]);
        nt_store_f4(make_float4(sx * inv, sy * inv, sz * inv, sw * inv),
                    &o[SPAN_HF4 + c]);
        nt_store_f4(last, &o[2 * SPAN_HF4 + c]);
    }
}

// ----------------------------------------------------------------- launcher

extern "C" void kernel_launch(void* const* d_in, const int* in_sizes, int n_in,
                              void* d_out, int out_size, void* d_ws, size_t ws_size,
                              hipStream_t stream) {
    const float4* hidden  = (const float4*)d_in[0];
    const int* span_doc   = (const int*)d_in[1];
    const int* span_tok   = (const int*)d_in[2];
    const int* span_len   = (const int*)d_in[3];
    const int* pair_i     = (const int*)d_in[4];
    const int* pair_j     = (const int*)d_in[5];
    float4* out           = (float4*)d_out;

    const int n_spans = in_sizes[1];      // 4096
    const int n_pairs = in_sizes[4];      // 16384

    // Workspace layout (16B-aligned sections):
    //   counts  : n_spans ints
    //   offsets : n_spans+1 ints
    //   cursor  : n_spans ints
    //   targets : 2*n_pairs ints
    auto align16 = [](size_t x) { return (x + 15) & ~(size_t)15; };
    const size_t counts_b  = align16((size_t)n_spans * sizeof(int));
    const size_t offsets_b = align16((size_t)(n_spans + 1) * sizeof(int));
    const size_t cursor_b  = align16((size_t)n_spans * sizeof(int));
    const size_t targets_b = align16((size_t)2 * n_pairs * sizeof(int));
    const size_t need = counts_b + offsets_b + cursor_b + targets_b;

    if (n_spans <= MAX_SPANS && ws_size >= need) {
        char* ws = (char*)d_ws;
        int* counts  = (int*)(ws);
        int* offsets = (int*)(ws + counts_b);
        int* cursor  = (int*)(ws + counts_b + offsets_b);
        int* targets = (int*)(ws + counts_b + offsets_b + cursor_b);

        const int zb = (n_spans + 255) / 256;
        const int pb = (n_pairs + 255) / 256;
        zero_counts_kernel<<<zb, 256, 0, stream>>>(counts, n_spans);
        count_uses_kernel<<<pb, 256, 0, stream>>>(pair_i, pair_j, counts, n_pairs);
        scan_offsets_kernel<<<1, 1024, 0, stream>>>(counts, offsets, cursor, n_spans);
        fill_targets_kernel<<<pb, 256, 0, stream>>>(pair_i, pair_j, cursor, targets, n_pairs);
        span_scatter_kernel<<<n_spans, 192, 0, stream>>>(
            hidden, span_doc, span_tok, span_len, offsets, targets, out, n_spans);
    } else {
        span_fused_kernel<<<n_pairs, 192, 0, stream>>>(
            hidden, span_doc, span_tok, span_len, pair_i, pair_j, out);
    }
}